// Round 19
// baseline (1221.429 us; speedup 1.0000x reference)
//
#include <hip/hip_runtime.h>
#include <hip/hip_bf16.h>
#include <cstdint>

// EdgeFrontierPolicy: E=400000, G=64, H=256.
// Producer/consumer wave specialization (r19): 512 threads/block.
//   waves 0-3 (consumers): r14-verified acc[2][4] MFMA path, two row-half
//     passes per GEMM (rows 0-31 then 32-63) -> full 64x256 tile
//   waves 4-7 (producers): r16-verified single-pass LN of tile k+1 into the
//     other A-buffer (concurrent with consumers' GEMMs -> HBM/VALU overlap
//     MFMA/L2 instead of phase-serializing)
// Double-buffered 2x32KB A-tiles; TPB=10 CONTIGUOUS tiles per block (keeps
// the launch-order tok locality that persistence destroyed in r11/r18).
// 5 uniform __syncthreads per tile. (512,4): est ~105 regs <= 128 budget.

typedef __bf16 bf16x8 __attribute__((ext_vector_type(8)));
typedef float  f32x4  __attribute__((ext_vector_type(4)));

__device__ __forceinline__ float gelu_f(float x) {
  float x2 = x * x;
  float t1 = __builtin_fmaf(0.1029444f, x2, 2.3022078f);
  float a  = x * t1;
  float e;
  asm("v_exp_f32 %0, %1" : "=v"(e) : "v"(a));
  float r;
  asm("v_rcp_f32 %0, %1" : "=v"(r) : "v"(e + 1.0f));
  return x - x * r;
}

__device__ __forceinline__ bf16x8 as_frag(uint4 u) {
  union { uint4 u; bf16x8 f; } c; c.u = u; return c.f;
}

// ---------------------------------------------------------------------------
// Pack W1 (ln1_g folded) / W2 into MFMA-B fragment order, bf16.
__global__ void prep_pack(const float* __restrict__ W1, const float* __restrict__ W2,
                          const float* __restrict__ ln1g,
                          __bf16* __restrict__ W1p, __bf16* __restrict__ W2p) {
  int gid = blockIdx.x * blockDim.x + threadIdx.x;   // 16384 threads
  int m  = gid >> 13;
  int b  = (gid >> 6) & 127;
  int l  = gid & 63;
  int kt = b >> 4, nt = b & 15;
  int k0 = kt * 32 + ((l >> 4) << 3);
  int n  = nt * 16 + (l & 15);
  const float* W = m ? W2 : W1;
  bf16x8 v;
#pragma unroll
  for (int i = 0; i < 8; ++i) {
    int k = k0 + i;
    float wv = W[k * 256 + n];
    if (!m) wv *= ln1g[k];
    v[i] = (__bf16)wv;
  }
  __bf16* dst = m ? W2p : W1p;
  *(bf16x8*)(dst + (size_t)(b * 64 + l) * 8) = v;
}

// C0/GW6/GW7 + mask dtype detect.
__global__ void prep_vec(const float* __restrict__ W1, const float* __restrict__ ln1g,
                         const float* __restrict__ ln1b, const float* __restrict__ b1,
                         const unsigned* __restrict__ smask_words,
                         float* __restrict__ C0, float* __restrict__ GW6,
                         float* __restrict__ GW7, int* __restrict__ maskIsByte) {
  __shared__ float red[4][256];
  const int n = threadIdx.x & 255, c = threadIdx.x >> 8;
  const int k0 = c * 64, k1 = (c == 3) ? 258 : k0 + 64;
  float s = 0.f;
#pragma unroll 4
  for (int k = k0; k < k1; ++k) s += ln1b[k] * W1[k * 256 + n];
  red[c][n] = s;
  __syncthreads();
  if (c == 0) {
    C0[n]  = b1[n] + red[0][n] + red[1][n] + red[2][n] + red[3][n];
    GW6[n] = ln1g[256] * W1[256 * 256 + n];
    GW7[n] = ln1g[257] * W1[257 * 256 + n];
  }
  if (threadIdx.x == 0) {
    int big = 0;
    for (int i = 0; i < 64; ++i) { if (smask_words[i] > 1u) big = 1; }
    *maskIsByte = big;
  }
}

// ---------------------------------------------------------------------------
#define EPB 64
#define TPB 10

// 8 K-steps; B-frags from L2, depth-1 reg double-buffer (r14-verified).
__device__ __forceinline__ void gemm8_reg2(const char* __restrict__ Wp,
                                           const char* aBase, unsigned swA,
                                           unsigned gA, int bOff,
                                           f32x4 (&acc)[2][4]) {
#pragma unroll
  for (int kt = 0; kt < 8; ++kt) {
    uint4 bn[4];
    if (kt == 0) {
#pragma unroll
      for (int cf = 0; cf < 4; ++cf)
        bn[cf] = *(const uint4*)(Wp + bOff + (cf << 10));
    }
    static uint4 dummy;  (void)dummy;
    uint4 bv[4];
#pragma unroll
    for (int cf = 0; cf < 4; ++cf)
      bv[cf] = *(const uint4*)(Wp + kt * 16384 + bOff + (cf << 10));
    bf16x8 av[2];
#pragma unroll
    for (int rf = 0; rf < 2; ++rf)
      av[rf] = *(const bf16x8*)(aBase + rf * 8192 + (((unsigned)(kt * 64) + gA) ^ swA));
#pragma unroll
    for (int rf = 0; rf < 2; ++rf)
#pragma unroll
      for (int cf = 0; cf < 4; ++cf)
        acc[rf][cf] = __builtin_amdgcn_mfma_f32_16x16x32_bf16(av[rf], as_frag(bv[cf]),
                                                              acc[rf][cf], 0, 0, 0);
  }
}

__global__ __launch_bounds__(512, 4) void edge_kernel(
    const float* __restrict__ tok, const int* __restrict__ ebatch,
    const unsigned char* __restrict__ smaskB,
    const int* __restrict__ eheads, const int* __restrict__ etails,
    const int* __restrict__ curtail,
    const __bf16* __restrict__ W1p, const __bf16* __restrict__ W2p,
    const float* __restrict__ C0v, const float* __restrict__ GW6v,
    const float* __restrict__ GW7v, const float* __restrict__ b2v,
    const float* __restrict__ selwv, const float* __restrict__ selbv,
    const int* __restrict__ maskFlag,
    float* __restrict__ outLogits, float* __restrict__ pooledAcc,
    float* __restrict__ cnts, int nTiles) {
  __shared__ __align__(16) char As_[2][32768];          // 2 A-buffers, swizzled
  __shared__ float sZa0[2][64], sZa1[2][64], sFront[2][64];
  __shared__ float sLog[64][4];
  __shared__ int sG[2][64];

  const int t = threadIdx.x;
  const int w = t >> 6, l = t & 63;
  const int mb = *maskFlag;
  const int kBeg = blockIdx.x * TPB;
  if (kBeg >= nTiles) return;                     // uniform per block
  const int kEnd = (kBeg + TPB < nTiles) ? (kBeg + TPB) : nTiles;

  // consumer constants (waves 0-3)
  const int rA = l & 15;
  const int r0 = (l >> 4) << 2;
  const unsigned swA = (unsigned)(rA & 7) << 4;
  const unsigned gA  = (unsigned)((l >> 4) << 4);
  const int cw   = w & 3;
  const int bOff = (cw << 12) + (l << 4);
  const char* W1c = (const char*)W1p;
  const char* W2c = (const char*)W2p;

  // producer: single-pass LN of `tile` into buffer nb (r16-verified math)
  auto produceLN = [&](int tile, int nb) {
    const int tp = t - 256, e = tp >> 2, q = tp & 3;
    const int ge = tile * EPB + e;
    const float* rp = tok + (size_t)ge * 256 + q * 4;
    float4 v[16];
    float s = 0.f, s2 = 0.f;
#pragma unroll
    for (int j = 0; j < 16; ++j) {
      v[j] = *(const float4*)(rp + j * 16);
      s  += v[j].x + v[j].y + v[j].z + v[j].w;
      s2 += v[j].x * v[j].x + v[j].y * v[j].y + v[j].z * v[j].z + v[j].w * v[j].w;
    }
    float candf = 0.f, frontf = 0.f;
    if (q == 0) {
      int g  = ebatch[ge];
      int mv = mb ? (int)smaskB[ge] : ((const int*)smaskB)[ge];
      int cand = (mv == 0);
      int cur  = curtail[g];
      int fr   = cand && ((eheads[ge] == cur) || (etails[ge] == cur));
      candf = (float)cand; frontf = (float)fr;
      sFront[nb][e] = (float)fr; sG[nb][e] = g;
    }
    const float a0 = __shfl(candf,  l & 60);
    const float a1 = __shfl(frontf, l & 60);
    s  += __shfl_xor(s, 1);  s  += __shfl_xor(s, 2);
    s2 += __shfl_xor(s2, 1); s2 += __shfl_xor(s2, 2);
    s += a0 + a1; s2 += a0 + a1;                  // 0/1 flags: x == x^2
    const float mean = s * (1.0f / 258.0f);
    const float var  = s2 * (1.0f / 258.0f) - mean * mean;
    const float rstd = rsqrtf(var + 1e-5f);
    const float nm   = -mean * rstd;
    const unsigned sw = (unsigned)(e & 7) << 4;
#pragma unroll
    for (int j = 0; j < 16; ++j) {
      union { __bf16 h[4]; uint2 u; } cv;
      cv.h[0] = (__bf16)__builtin_fmaf(v[j].x, rstd, nm);
      cv.h[1] = (__bf16)__builtin_fmaf(v[j].y, rstd, nm);
      cv.h[2] = (__bf16)__builtin_fmaf(v[j].z, rstd, nm);
      cv.h[3] = (__bf16)__builtin_fmaf(v[j].w, rstd, nm);
      unsigned off = (unsigned)(q * 8 + j * 32);
      *(uint2*)(As_[nb] + e * 512 + (off ^ sw)) = cv.u;
    }
    if (q == 0) {
      sZa0[nb][e] = __builtin_fmaf(a0, rstd, nm);
      sZa1[nb][e] = __builtin_fmaf(a1, rstd, nm);
    }
  };

  // ---- prologue: producers fill buf 0 with tile kBeg ----
  if (t >= 256) produceLN(kBeg, 0);
  __syncthreads();

  f32x4 acc[2][4];

  for (int k = kBeg; k < kEnd; ++k) {
    const int buf = (k - kBeg) & 1, nb = buf ^ 1;
    const int base = k * EPB;

    // ==== Seg1: C: counts + accinit-h0 + G1-h0 | P: LN(k+1) -> nb ====
    if (t < 256) {
      if (t == 0) {   // counts for tile k (sG[buf] stable since last barrier)
        int cg = sG[buf][0]; float run = 1.f;
        for (int ee = 1; ee < EPB; ++ee) {
          int g = sG[buf][ee];
          if (g == cg) run += 1.f;
          else { atomicAdd(&cnts[cg], run); cg = g; run = 1.f; }
        }
        atomicAdd(&cnts[cg], run);
      }
      float c0r[4], w6r[4], w7r[4];
#pragma unroll
      for (int cf = 0; cf < 4; ++cf) {
        int col = cw * 64 + cf * 16 + rA;
        c0r[cf] = C0v[col]; w6r[cf] = GW6v[col]; w7r[cf] = GW7v[col];
      }
      f32x4 za0q[2], za1q[2];
#pragma unroll
      for (int rf = 0; rf < 2; ++rf) {
        za0q[rf] = *(const f32x4*)&sZa0[buf][rf * 16 + r0];
        za1q[rf] = *(const f32x4*)&sZa1[buf][rf * 16 + r0];
      }
#pragma unroll
      for (int rf = 0; rf < 2; ++rf)
#pragma unroll
        for (int cf = 0; cf < 4; ++cf)
#pragma unroll
          for (int i = 0; i < 4; ++i)
            acc[rf][cf][i] = c0r[cf] + za0q[rf][i] * w6r[cf] + za1q[rf][i] * w7r[cf];
      gemm8_reg2(W1c, As_[buf] + rA * 512, swA, gA, bOff, acc);
    } else if (k + 1 < kEnd) {
      produceLN(k + 1, nb);
    }
    __syncthreads();   // b1: all G1-h0 zln reads (rows 0-31) complete

    // ==== Seg2: C: epi1-h0 (h1 rows 0-31), accinit-h1, G1-h1 ====
    if (t < 256) {
#pragma unroll
      for (int rf = 0; rf < 2; ++rf)
#pragma unroll
        for (int i = 0; i < 4; ++i) {
          int row = rf * 16 + r0 + i;
          char* rowp = As_[buf] + row * 512;
          unsigned sw = (unsigned)(row & 7) << 4;
#pragma unroll
          for (int cf = 0; cf < 4; ++cf) {
            int col = cw * 64 + cf * 16 + rA;
            *(__bf16*)(rowp + (((unsigned)(col * 2)) ^ sw)) = (__bf16)gelu_f(acc[rf][cf][i]);
          }
        }
      float c0r[4], w6r[4], w7r[4];
#pragma unroll
      for (int cf = 0; cf < 4; ++cf) {
        int col = cw * 64 + cf * 16 + rA;
        c0r[cf] = C0v[col]; w6r[cf] = GW6v[col]; w7r[cf] = GW7v[col];
      }
      f32x4 za0q[2], za1q[2];
#pragma unroll
      for (int rf = 0; rf < 2; ++rf) {
        za0q[rf] = *(const f32x4*)&sZa0[buf][32 + rf * 16 + r0];
        za1q[rf] = *(const f32x4*)&sZa1[buf][32 + rf * 16 + r0];
      }
#pragma unroll
      for (int rf = 0; rf < 2; ++rf)
#pragma unroll
        for (int cf = 0; cf < 4; ++cf)
#pragma unroll
          for (int i = 0; i < 4; ++i)
            acc[rf][cf][i] = c0r[cf] + za0q[rf][i] * w6r[cf] + za1q[rf][i] * w7r[cf];
      gemm8_reg2(W1c, As_[buf] + (32 + rA) * 512, swA, gA, bOff, acc);
    }
    __syncthreads();   // b2: G1-h1 zln reads done; h1 rows 0-31 visible

    // ==== Seg3: C: epi1-h1 (h1 rows 32-63), G2-h0 + epi2-h0 ====
    if (t < 256) {
#pragma unroll
      for (int rf = 0; rf < 2; ++rf)
#pragma unroll
        for (int i = 0; i < 4; ++i) {
          int row = 32 + rf * 16 + r0 + i;
          char* rowp = As_[buf] + row * 512;
          unsigned sw = (unsigned)(row & 7) << 4;
#pragma unroll
          for (int cf = 0; cf < 4; ++cf) {
            int col = cw * 64 + cf * 16 + rA;
            *(__bf16*)(rowp + (((unsigned)(col * 2)) ^ sw)) = (__bf16)gelu_f(acc[rf][cf][i]);
          }
        }
#pragma unroll
      for (int cf = 0; cf < 4; ++cf) {
        float bb = b2v[cw * 64 + cf * 16 + rA];
#pragma unroll
        for (int rf = 0; rf < 2; ++rf)
#pragma unroll
          for (int i = 0; i < 4; ++i) acc[rf][cf][i] = bb;
      }
      gemm8_reg2(W2c, As_[buf] + rA * 512, swA, gA, bOff, acc);
      // epi2-h0
      float lwr[4];
#pragma unroll
      for (int cf = 0; cf < 4; ++cf) lwr[cf] = selwv[cw * 64 + cf * 16 + rA];
#pragma unroll
      for (int rf = 0; rf < 2; ++rf)
#pragma unroll
        for (int cf = 0; cf < 4; ++cf)
#pragma unroll
          for (int i = 0; i < 4; ++i) acc[rf][cf][i] = gelu_f(acc[rf][cf][i]);
#pragma unroll
      for (int rf = 0; rf < 2; ++rf)
#pragma unroll
        for (int i = 0; i < 4; ++i) {
          float p = acc[rf][0][i] * lwr[0] + acc[rf][1][i] * lwr[1]
                  + acc[rf][2][i] * lwr[2] + acc[rf][3][i] * lwr[3];
          p += __shfl_xor(p, 1); p += __shfl_xor(p, 2);
          p += __shfl_xor(p, 4); p += __shfl_xor(p, 8);
          if (rA == 0) sLog[rf * 16 + r0 + i][cw] = p;
        }
      if (sG[buf][0] == sG[buf][EPB - 1]) {
        int g = sG[buf][0];
#pragma unroll
        for (int cf = 0; cf < 4; ++cf) {
          float sv = 0.f;
#pragma unroll
          for (int rf = 0; rf < 2; ++rf)
#pragma unroll
            for (int i = 0; i < 4; ++i) sv += acc[rf][cf][i];
          sv += __shfl_xor(sv, 16);
          sv += __shfl_xor(sv, 32);
          if (l < 16) atomicAdd(&pooledAcc[g * 256 + cw * 64 + cf * 16 + l], sv);
        }
      } else {
#pragma unroll
        for (int rf = 0; rf < 2; ++rf)
#pragma unroll
          for (int i = 0; i < 4; ++i) {
            int row = rf * 16 + r0 + i;
            int g = sG[buf][row];
#pragma unroll
            for (int cf = 0; cf < 4; ++cf)
              atomicAdd(&pooledAcc[g * 256 + cw * 64 + cf * 16 + rA], acc[rf][cf][i]);
          }
      }
    }
    __syncthreads();   // b3: h1 rows 32-63 visible

    // ==== Seg4: C: G2-h1 + epi2-h1 ====
    if (t < 256) {
#pragma unroll
      for (int cf = 0; cf < 4; ++cf) {
        float bb = b2v[cw * 64 + cf * 16 + rA];
#pragma unroll
        for (int rf = 0; rf < 2; ++rf)
#pragma unroll
          for (int i = 0; i < 4; ++i) acc[rf][cf][i] = bb;
      }
      gemm8_reg2(W2c, As_[buf] + (32 + rA) * 512, swA, gA, bOff, acc);
      float lwr[4];
#pragma unroll
      for (int cf = 0; cf < 4; ++cf) lwr[cf] = selwv[cw * 64 + cf * 16 + rA];
#pragma unroll
      for (int rf = 0; rf < 2; ++rf)
#pragma unroll
        for (int cf = 0; cf < 4; ++cf)
#pragma unroll
          for (int i = 0; i < 4; ++i) acc[rf][cf][i] = gelu_f(acc[rf][cf][i]);
#pragma unroll
      for (int rf = 0; rf < 2; ++rf)
#pragma unroll
        for (int i = 0; i < 4; ++i) {
          float p = acc[rf][0][i] * lwr[0] + acc[rf][1][i] * lwr[1]
                  + acc[rf][2][i] * lwr[2] + acc[rf][3][i] * lwr[3];
          p += __shfl_xor(p, 1); p += __shfl_xor(p, 2);
          p += __shfl_xor(p, 4); p += __shfl_xor(p, 8);
          if (rA == 0) sLog[32 + rf * 16 + r0 + i][cw] = p;
        }
      if (sG[buf][0] == sG[buf][EPB - 1]) {
        int g = sG[buf][0];
#pragma unroll
        for (int cf = 0; cf < 4; ++cf) {
          float sv = 0.f;
#pragma unroll
          for (int rf = 0; rf < 2; ++rf)
#pragma unroll
            for (int i = 0; i < 4; ++i) sv += acc[rf][cf][i];
          sv += __shfl_xor(sv, 16);
          sv += __shfl_xor(sv, 32);
          if (l < 16) atomicAdd(&pooledAcc[g * 256 + cw * 64 + cf * 16 + l], sv);
        }
      } else {
#pragma unroll
        for (int rf = 0; rf < 2; ++rf)
#pragma unroll
          for (int i = 0; i < 4; ++i) {
            int row = 32 + rf * 16 + r0 + i;
            int g = sG[buf][row];
#pragma unroll
            for (int cf = 0; cf < 4; ++cf)
              atomicAdd(&pooledAcc[g * 256 + cw * 64 + cf * 16 + rA], acc[rf][cf][i]);
          }
      }
    }
    __syncthreads();   // b4: sLog complete

    // ==== Seg5: logits out ====
    if (t < 64)
      outLogits[base + t] = sLog[t][0] + sLog[t][1] + sLog[t][2] + sLog[t][3]
                          + selbv[0] + 0.5f * sFront[buf][t];
    __syncthreads();   // b5: sLog/sFront/As_[buf] free for reuse
  }
}

// ---------------------------------------------------------------------------
__global__ __launch_bounds__(256) void stop_kernel(
    const float* __restrict__ pooledAcc, const float* __restrict__ cnts,
    const float* __restrict__ qtok,
    const float* __restrict__ ln2g, const float* __restrict__ ln2b,
    const float* __restrict__ sW1, const float* __restrict__ sb1,
    const float* __restrict__ sW2, const float* __restrict__ sb2,
    float* __restrict__ outStop, float* __restrict__ outPooled) {
  __shared__ float sIn[512], sLn[512], sRed[8];
  const int t = threadIdx.x, g = blockIdx.x;
  const int w = t >> 6, l = t & 63;
  float c = fmaxf(cnts[g], 1.0f);
  float p = pooledAcc[g * 256 + t] / c;
  outPooled[g * 256 + t] = p;
  sIn[t] = p;
  sIn[256 + t] = qtok[g * 256 + t];
  __syncthreads();
  float a = sIn[t], b = sIn[256 + t];
  float s = a + b, s2 = a * a + b * b;
#pragma unroll
  for (int m = 1; m < 64; m <<= 1) { s += __shfl_xor(s, m); s2 += __shfl_xor(s2, m); }
  if (l == 0) { sRed[w] = s; sRed[4 + w] = s2; }
  __syncthreads();
  s  = sRed[0] + sRed[1] + sRed[2] + sRed[3];
  s2 = sRed[4] + sRed[5] + sRed[6] + sRed[7];
  const float mean = s * (1.0f / 512.0f);
  const float var  = s2 * (1.0f / 512.0f) - mean * mean;
  const float rstd = rsqrtf(var + 1e-5f);
  sLn[t]       = (a - mean) * rstd * ln2g[t] + ln2b[t];
  sLn[256 + t] = (b - mean) * rstd * ln2g[256 + t] + ln2b[256 + t];
  __syncthreads();
  float accv = sb1[t];
#pragma unroll 8
  for (int k = 0; k < 512; ++k) accv += sLn[k] * sW1[k * 256 + t];
  float u = gelu_f(accv);
  float part = u * sW2[t];
#pragma unroll
  for (int m = 1; m < 64; m <<= 1) part += __shfl_xor(part, m);
  if (l == 0) sRed[w] = part;
  __syncthreads();
  if (t == 0) outStop[g] = sRed[0] + sRed[1] + sRed[2] + sRed[3] + sb2[0];
}

// ---------------------------------------------------------------------------
extern "C" void kernel_launch(void* const* d_in, const int* in_sizes, int n_in,
                              void* d_out, int out_size, void* d_ws, size_t ws_size,
                              hipStream_t stream) {
  const float* tok   = (const float*)d_in[0];
  const float* qtok  = (const float*)d_in[1];
  const int* ebatch  = (const int*)d_in[2];
  const void* smask  = d_in[3];
  const int* eheads  = (const int*)d_in[4];
  const int* etails  = (const int*)d_in[5];
  const int* curtail = (const int*)d_in[6];
  const float* ln1g  = (const float*)d_in[7];
  const float* ln1b  = (const float*)d_in[8];
  const float* W1    = (const float*)d_in[9];
  const float* b1    = (const float*)d_in[10];
  const float* W2    = (const float*)d_in[11];
  const float* b2    = (const float*)d_in[12];
  const float* selw  = (const float*)d_in[13];
  const float* selb  = (const float*)d_in[14];
  const float* ln2g  = (const float*)d_in[15];
  const float* ln2b  = (const float*)d_in[16];
  const float* sW1   = (const float*)d_in[17];
  const float* sb1   = (const float*)d_in[18];
  const float* sW2   = (const float*)d_in[19];
  const float* sb2   = (const float*)d_in[20];

  const int E = in_sizes[2];            // 400000
  const int G = in_sizes[1] / 256;      // 64
  const int nTiles = E / EPB;           // 6250
  const int grid = (nTiles + TPB - 1) / TPB;   // 625

  char* ws = (char*)d_ws;
  __bf16* W1p   = (__bf16*)(ws);                 // 131072 B
  __bf16* W2p   = (__bf16*)(ws + 131072);        // 131072 B
  float*  C0    = (float*)(ws + 262144);
  float*  GW6   = (float*)(ws + 263168);
  float*  GW7   = (float*)(ws + 264192);
  float*  pooled= (float*)(ws + 265216);         // 65536 B
  float*  cnts  = (float*)(ws + 330752);         // 256 B
  int*    mflag = (int*)(ws + 331008);           // 4 B
  (void)ws_size; (void)n_in; (void)out_size;

  hipMemsetAsync(ws + 265216, 0, 65536 + 256, stream);  // pooled + counts

  prep_pack<<<64, 256, 0, stream>>>(W1, W2, ln1g, W1p, W2p);
  prep_vec<<<1, 1024, 0, stream>>>(W1, ln1g, ln1b, b1, (const unsigned*)smask,
                                   C0, GW6, GW7, mflag);
  edge_kernel<<<grid, 512, 0, stream>>>(
      tok, ebatch, (const unsigned char*)smask, eheads, etails, curtail,
      W1p, W2p, C0, GW6, GW7, b2, selw, selb, mflag,
      (float*)d_out, pooled, cnts, nTiles);
  stop_kernel<<<G, 256, 0, stream>>>(pooled, cnts, qtok, ln2g, ln2b,
                                     sW1, sb1, sW2, sb2,
                                     (float*)d_out + E, (float*)d_out + E + G);
}

// Round 20
// 917.653 us; speedup vs baseline: 1.3310x; 1.3310x over previous
//
#include <hip/hip_runtime.h>
#include <hip/hip_bf16.h>
#include <cstdint>

// EdgeFrontierPolicy: E=400000, G=64, H=256.
// r20: producer/consumer built ONLY from r16-verified parts.
//   consumers (waves 0-3): r16's acc[4][4] + prefetching gemm8_pre + epilogues
//   producers (waves 4-7): r16's single-pass LN for tile k+1, with load
//     issuance SPLIT across segments (j0-7 | j8-15 | flags | stats+store) so
//     HBM latency rides under the consumers' GEMM phases
// Raw `s_waitcnt lgkmcnt(0); s_barrier` (memory-clobber asm) at phase edges:
// LDS handoffs fenced, but producers' global loads stay IN FLIGHT across
// barriers (unlike __syncthreads' vmcnt(0) drain).
// (512,2): 256-reg budget; static live ~206 (pv64+acc64+wb016+misc) -> no
// spill (r19's VGPR=64 squeeze chunked the LN burst and doubled FETCH).
// 250 blocks x 25 contiguous tiles, 1 block/CU (8 waves at ~200 regs).

typedef __bf16 bf16x8 __attribute__((ext_vector_type(8)));
typedef float  f32x4  __attribute__((ext_vector_type(4)));

#define BAR() asm volatile("s_waitcnt lgkmcnt(0)\n\ts_barrier" ::: "memory")

__device__ __forceinline__ float gelu_f(float x) {
  float x2 = x * x;
  float t1 = __builtin_fmaf(0.1029444f, x2, 2.3022078f);
  float a  = x * t1;
  float e;
  asm("v_exp_f32 %0, %1" : "=v"(e) : "v"(a));
  float r;
  asm("v_rcp_f32 %0, %1" : "=v"(r) : "v"(e + 1.0f));
  return x - x * r;
}

__device__ __forceinline__ bf16x8 as_frag(uint4 u) {
  union { uint4 u; bf16x8 f; } c; c.u = u; return c.f;
}

// ---------------------------------------------------------------------------
// Pack W1 (ln1_g folded) / W2 into MFMA-B fragment order, bf16.
__global__ void prep_pack(const float* __restrict__ W1, const float* __restrict__ W2,
                          const float* __restrict__ ln1g,
                          __bf16* __restrict__ W1p, __bf16* __restrict__ W2p) {
  int gid = blockIdx.x * blockDim.x + threadIdx.x;   // 16384 threads
  int m  = gid >> 13;
  int b  = (gid >> 6) & 127;
  int l  = gid & 63;
  int kt = b >> 4, nt = b & 15;
  int k0 = kt * 32 + ((l >> 4) << 3);
  int n  = nt * 16 + (l & 15);
  const float* W = m ? W2 : W1;
  bf16x8 v;
#pragma unroll
  for (int i = 0; i < 8; ++i) {
    int k = k0 + i;
    float wv = W[k * 256 + n];
    if (!m) wv *= ln1g[k];
    v[i] = (__bf16)wv;
  }
  __bf16* dst = m ? W2p : W1p;
  *(bf16x8*)(dst + (size_t)(b * 64 + l) * 8) = v;
}

// C0/GW6/GW7 + mask dtype detect.
__global__ void prep_vec(const float* __restrict__ W1, const float* __restrict__ ln1g,
                         const float* __restrict__ ln1b, const float* __restrict__ b1,
                         const unsigned* __restrict__ smask_words,
                         float* __restrict__ C0, float* __restrict__ GW6,
                         float* __restrict__ GW7, int* __restrict__ maskIsByte) {
  __shared__ float red[4][256];
  const int n = threadIdx.x & 255, c = threadIdx.x >> 8;
  const int k0 = c * 64, k1 = (c == 3) ? 258 : k0 + 64;
  float s = 0.f;
#pragma unroll 4
  for (int k = k0; k < k1; ++k) s += ln1b[k] * W1[k * 256 + n];
  red[c][n] = s;
  __syncthreads();
  if (c == 0) {
    C0[n]  = b1[n] + red[0][n] + red[1][n] + red[2][n] + red[3][n];
    GW6[n] = ln1g[256] * W1[256 * 256 + n];
    GW7[n] = ln1g[257] * W1[257 * 256 + n];
  }
  if (threadIdx.x == 0) {
    int big = 0;
    for (int i = 0; i < 64; ++i) { if (smask_words[i] > 1u) big = 1; }
    *maskIsByte = big;
  }
}

// ---------------------------------------------------------------------------
#define EPB 64
#define TPB 25

// 8 K-steps; kt0 B-frags arrive preloaded in bv; depth-1 double-buffer
// (r16-verified verbatim).
__device__ __forceinline__ void gemm8_pre(const char* __restrict__ Wp,
                                          const char* aBase, unsigned swA,
                                          unsigned gA, int bOff,
                                          uint4 (&bv)[4], f32x4 (&acc)[4][4]) {
#pragma unroll
  for (int kt = 0; kt < 8; ++kt) {
    uint4 bn[4];
    if (kt < 7) {
#pragma unroll
      for (int cf = 0; cf < 4; ++cf)
        bn[cf] = *(const uint4*)(Wp + (kt + 1) * 16384 + bOff + (cf << 10));
    }
    bf16x8 av[4];
#pragma unroll
    for (int rf = 0; rf < 4; ++rf)
      av[rf] = *(const bf16x8*)(aBase + rf * 8192 + (((unsigned)(kt * 64) + gA) ^ swA));
#pragma unroll
    for (int rf = 0; rf < 4; ++rf)
#pragma unroll
      for (int cf = 0; cf < 4; ++cf)
        acc[rf][cf] = __builtin_amdgcn_mfma_f32_16x16x32_bf16(av[rf], as_frag(bv[cf]),
                                                              acc[rf][cf], 0, 0, 0);
#pragma unroll
    for (int cf = 0; cf < 4; ++cf) bv[cf] = bn[cf];
  }
}

__global__ __launch_bounds__(512, 2) void edge_kernel(
    const float* __restrict__ tok, const int* __restrict__ ebatch,
    const unsigned char* __restrict__ smaskB,
    const int* __restrict__ eheads, const int* __restrict__ etails,
    const int* __restrict__ curtail,
    const __bf16* __restrict__ W1p, const __bf16* __restrict__ W2p,
    const float* __restrict__ C0v, const float* __restrict__ GW6v,
    const float* __restrict__ GW7v, const float* __restrict__ b2v,
    const float* __restrict__ selwv, const float* __restrict__ selbv,
    const int* __restrict__ maskFlag,
    float* __restrict__ outLogits, float* __restrict__ pooledAcc,
    float* __restrict__ cnts, int nTiles) {
  __shared__ __align__(16) char As_[2][32768];          // 2 A-buffers, swizzled
  __shared__ float sZa0[2][64], sZa1[2][64], sFront[2][64];
  __shared__ float sLog[64][4];
  __shared__ int sG[2][64];

  const int t = threadIdx.x;
  const int w = t >> 6, l = t & 63;
  const int mb = *maskFlag;
  const int kBeg = blockIdx.x * TPB;
  if (kBeg >= nTiles) return;                     // uniform per block
  const int kEnd = (kBeg + TPB < nTiles) ? (kBeg + TPB) : nTiles;

  // consumer constants (waves 0-3)
  const int rA = l & 15;
  const int r0 = (l >> 4) << 2;
  const unsigned swA = (unsigned)(rA & 7) << 4;
  const unsigned gA  = (unsigned)((l >> 4) << 4);
  const int cw   = w & 3;
  const int bOff = (cw << 12) + (l << 4);
  const char* W1c = (const char*)W1p;
  const char* W2c = (const char*)W2p;

  // producer mapping (waves 4-7): 4 threads/edge
  const int pe = (t - 256) >> 2, pq = (t - 256) & 3;

  // producer state (lives across segments; only producer branches touch it)
  float4 pv[16];
  float pcand = 0.f, pfront = 0.f;
  uint4 wb0[4];           // consumer B-frag preload (W1-kt0 / W2-kt0)
  f32x4 acc[4][4];

  // ---- prologue ----
  if (t < 256) {
    // preload W1-kt0 for first G1 (pending into SegA)
#pragma unroll
    for (int cf = 0; cf < 4; ++cf)
      wb0[cf] = *(const uint4*)(W1c + bOff + (cf << 10));
  } else {
    // full LN of tile kBeg into buffer 0 (r16-verified math)
    const int ge = kBeg * EPB + pe;
    const float* rp = tok + (size_t)ge * 256 + pq * 4;
    float s = 0.f, s2 = 0.f;
#pragma unroll
    for (int j = 0; j < 16; ++j) {
      pv[j] = *(const float4*)(rp + j * 16);
      s  += pv[j].x + pv[j].y + pv[j].z + pv[j].w;
      s2 += pv[j].x * pv[j].x + pv[j].y * pv[j].y + pv[j].z * pv[j].z + pv[j].w * pv[j].w;
    }
    float candf = 0.f, frontf = 0.f;
    if (pq == 0) {
      int g  = ebatch[ge];
      int mv = mb ? (int)smaskB[ge] : ((const int*)smaskB)[ge];
      int cand = (mv == 0);
      int cur  = curtail[g];
      int fr   = cand && ((eheads[ge] == cur) || (etails[ge] == cur));
      candf = (float)cand; frontf = (float)fr;
      sFront[0][pe] = (float)fr; sG[0][pe] = g;
    }
    const float a0 = __shfl(candf,  l & 60);
    const float a1 = __shfl(frontf, l & 60);
    s  += __shfl_xor(s, 1);  s  += __shfl_xor(s, 2);
    s2 += __shfl_xor(s2, 1); s2 += __shfl_xor(s2, 2);
    s += a0 + a1; s2 += a0 + a1;
    const float mean = s * (1.0f / 258.0f);
    const float var  = s2 * (1.0f / 258.0f) - mean * mean;
    const float rstd = rsqrtf(var + 1e-5f);
    const float nm   = -mean * rstd;
    const unsigned sw = (unsigned)(pe & 7) << 4;
#pragma unroll
    for (int j = 0; j < 16; ++j) {
      union { __bf16 h[4]; uint2 u; } cv;
      cv.h[0] = (__bf16)__builtin_fmaf(pv[j].x, rstd, nm);
      cv.h[1] = (__bf16)__builtin_fmaf(pv[j].y, rstd, nm);
      cv.h[2] = (__bf16)__builtin_fmaf(pv[j].z, rstd, nm);
      cv.h[3] = (__bf16)__builtin_fmaf(pv[j].w, rstd, nm);
      unsigned off = (unsigned)(pq * 8 + j * 32);
      *(uint2*)(As_[0] + pe * 512 + (off ^ sw)) = cv.u;
    }
    if (pq == 0) {
      sZa0[0][pe] = __builtin_fmaf(a0, rstd, nm);
      sZa1[0][pe] = __builtin_fmaf(a1, rstd, nm);
    }
  }
  BAR();

  int buf = 0;
  for (int k = kBeg; k < kEnd; ++k) {
    const int nb = buf ^ 1;
    const int base = k * EPB;
    const bool hasNext = (k + 1 < kEnd);
    const float* prp = hasNext ? (tok + (size_t)((k + 1) * EPB + pe) * 256 + pq * 4)
                               : nullptr;

    // ==== SegA: C: counts + accinit + G1 | P: issue pv[0..7] for k+1 ====
    if (t < 256) {
      if (t == 0) {
        int cg = sG[buf][0]; float run = 1.f;
        for (int ee = 1; ee < EPB; ++ee) {
          int g = sG[buf][ee];
          if (g == cg) run += 1.f;
          else { atomicAdd(&cnts[cg], run); cg = g; run = 1.f; }
        }
        atomicAdd(&cnts[cg], run);
      }
      float c0r[4], w6r[4], w7r[4];
#pragma unroll
      for (int cf = 0; cf < 4; ++cf) {
        int col = cw * 64 + cf * 16 + rA;
        c0r[cf] = C0v[col]; w6r[cf] = GW6v[col]; w7r[cf] = GW7v[col];
      }
      f32x4 za0q[4], za1q[4];
#pragma unroll
      for (int rf = 0; rf < 4; ++rf) {
        za0q[rf] = *(const f32x4*)&sZa0[buf][rf * 16 + r0];
        za1q[rf] = *(const f32x4*)&sZa1[buf][rf * 16 + r0];
      }
#pragma unroll
      for (int rf = 0; rf < 4; ++rf)
#pragma unroll
        for (int cf = 0; cf < 4; ++cf)
#pragma unroll
          for (int i = 0; i < 4; ++i)
            acc[rf][cf][i] = c0r[cf] + za0q[rf][i] * w6r[cf] + za1q[rf][i] * w7r[cf];
      gemm8_pre(W1c, As_[buf] + rA * 512, swA, gA, bOff, wb0, acc);
    } else if (hasNext) {
#pragma unroll
      for (int j = 0; j < 8; ++j) pv[j] = *(const float4*)(prp + j * 16);
    }
    BAR();   // b1: G1's A-reads complete block-wide

    // ==== SegB: C: preload W2-kt0, epi1 -> h1 into As_[buf] | P: pv[8..15] ====
    if (t < 256) {
#pragma unroll
      for (int cf = 0; cf < 4; ++cf)
        wb0[cf] = *(const uint4*)(W2c + bOff + (cf << 10));
#pragma unroll
      for (int rf = 0; rf < 4; ++rf)
#pragma unroll
        for (int i = 0; i < 4; ++i) {
          int row = rf * 16 + r0 + i;
          char* rowp = As_[buf] + row * 512;
          unsigned sw = (unsigned)(row & 7) << 4;
#pragma unroll
          for (int cf = 0; cf < 4; ++cf) {
            int col = cw * 64 + cf * 16 + rA;
            *(__bf16*)(rowp + (((unsigned)(col * 2)) ^ sw)) = (__bf16)gelu_f(acc[rf][cf][i]);
          }
        }
    } else if (hasNext) {
#pragma unroll
      for (int j = 8; j < 16; ++j) pv[j] = *(const float4*)(prp + j * 16);
    }
    BAR();   // b2: h1 visible

    // ==== SegC: C: G2 + epi2 (gelu, sLog write, pooled) | P: flags for k+1 ====
    if (t < 256) {
#pragma unroll
      for (int cf = 0; cf < 4; ++cf) {
        float bb = b2v[cw * 64 + cf * 16 + rA];
#pragma unroll
        for (int rf = 0; rf < 4; ++rf)
#pragma unroll
          for (int i = 0; i < 4; ++i) acc[rf][cf][i] = bb;
      }
      gemm8_pre(W2c, As_[buf] + rA * 512, swA, gA, bOff, wb0, acc);
#pragma unroll
      for (int rf = 0; rf < 4; ++rf)
#pragma unroll
        for (int cf = 0; cf < 4; ++cf)
#pragma unroll
          for (int i = 0; i < 4; ++i) acc[rf][cf][i] = gelu_f(acc[rf][cf][i]);
      {
        float lwr[4];
#pragma unroll
        for (int cf = 0; cf < 4; ++cf) lwr[cf] = selwv[cw * 64 + cf * 16 + rA];
#pragma unroll
        for (int rf = 0; rf < 4; ++rf)
#pragma unroll
          for (int i = 0; i < 4; ++i) {
            float p = acc[rf][0][i] * lwr[0] + acc[rf][1][i] * lwr[1]
                    + acc[rf][2][i] * lwr[2] + acc[rf][3][i] * lwr[3];
            p += __shfl_xor(p, 1); p += __shfl_xor(p, 2);
            p += __shfl_xor(p, 4); p += __shfl_xor(p, 8);
            if (rA == 0) sLog[rf * 16 + r0 + i][cw] = p;
          }
      }
      if (sG[buf][0] == sG[buf][EPB - 1]) {
        int g = sG[buf][0];
#pragma unroll
        for (int cf = 0; cf < 4; ++cf) {
          float sv = 0.f;
#pragma unroll
          for (int rf = 0; rf < 4; ++rf)
#pragma unroll
            for (int i = 0; i < 4; ++i) sv += acc[rf][cf][i];
          sv += __shfl_xor(sv, 16);
          sv += __shfl_xor(sv, 32);
          if (l < 16) atomicAdd(&pooledAcc[g * 256 + cw * 64 + cf * 16 + l], sv);
        }
      } else {
#pragma unroll
        for (int rf = 0; rf < 4; ++rf)
#pragma unroll
          for (int i = 0; i < 4; ++i) {
            int row = rf * 16 + r0 + i;
            int g = sG[buf][row];
#pragma unroll
            for (int cf = 0; cf < 4; ++cf)
              atomicAdd(&pooledAcc[g * 256 + cw * 64 + cf * 16 + rA], acc[rf][cf][i]);
          }
      }
    } else if (hasNext) {
      pcand = 0.f; pfront = 0.f;
      if (pq == 0) {
        const int ge = (k + 1) * EPB + pe;
        int g  = ebatch[ge];
        int mv = mb ? (int)smaskB[ge] : ((const int*)smaskB)[ge];
        int cand = (mv == 0);
        int cur  = curtail[g];
        int fr   = cand && ((eheads[ge] == cur) || (etails[ge] == cur));
        pcand = (float)cand; pfront = (float)fr;
        sFront[nb][pe] = (float)fr; sG[nb][pe] = g;
      }
    }
    BAR();   // b3: sLog visible; As_[buf] fully consumed

    // ==== SegD: C: logits out + preload W1-kt0 | P: stats+convert+store ====
    if (t < 256) {
      if (t < 64)
        outLogits[base + t] = sLog[t][0] + sLog[t][1] + sLog[t][2] + sLog[t][3]
                            + selbv[0] + 0.5f * sFront[buf][t];
#pragma unroll
      for (int cf = 0; cf < 4; ++cf)
        wb0[cf] = *(const uint4*)(W1c + bOff + (cf << 10));
    } else if (hasNext) {
      float s = 0.f, s2 = 0.f;
#pragma unroll
      for (int j = 0; j < 16; ++j) {
        s  += pv[j].x + pv[j].y + pv[j].z + pv[j].w;
        s2 += pv[j].x * pv[j].x + pv[j].y * pv[j].y + pv[j].z * pv[j].z + pv[j].w * pv[j].w;
      }
      const float a0 = __shfl(pcand,  l & 60);
      const float a1 = __shfl(pfront, l & 60);
      s  += __shfl_xor(s, 1);  s  += __shfl_xor(s, 2);
      s2 += __shfl_xor(s2, 1); s2 += __shfl_xor(s2, 2);
      s += a0 + a1; s2 += a0 + a1;               // 0/1 flags: x == x^2
      const float mean = s * (1.0f / 258.0f);
      const float var  = s2 * (1.0f / 258.0f) - mean * mean;
      const float rstd = rsqrtf(var + 1e-5f);
      const float nm   = -mean * rstd;
      const unsigned sw = (unsigned)(pe & 7) << 4;
#pragma unroll
      for (int j = 0; j < 16; ++j) {
        union { __bf16 h[4]; uint2 u; } cv;
        cv.h[0] = (__bf16)__builtin_fmaf(pv[j].x, rstd, nm);
        cv.h[1] = (__bf16)__builtin_fmaf(pv[j].y, rstd, nm);
        cv.h[2] = (__bf16)__builtin_fmaf(pv[j].z, rstd, nm);
        cv.h[3] = (__bf16)__builtin_fmaf(pv[j].w, rstd, nm);
        unsigned off = (unsigned)(pq * 8 + j * 32);
        *(uint2*)(As_[nb] + pe * 512 + (off ^ sw)) = cv.u;
      }
      if (pq == 0) {
        sZa0[nb][pe] = __builtin_fmaf(a0, rstd, nm);
        sZa1[nb][pe] = __builtin_fmaf(a1, rstd, nm);
      }
    }
    BAR();   // b4: As_[nb]/sZa[nb] ready; As_[buf] free
    buf = nb;
  }
}

// ---------------------------------------------------------------------------
__global__ __launch_bounds__(256) void stop_kernel(
    const float* __restrict__ pooledAcc, const float* __restrict__ cnts,
    const float* __restrict__ qtok,
    const float* __restrict__ ln2g, const float* __restrict__ ln2b,
    const float* __restrict__ sW1, const float* __restrict__ sb1,
    const float* __restrict__ sW2, const float* __restrict__ sb2,
    float* __restrict__ outStop, float* __restrict__ outPooled) {
  __shared__ float sIn[512], sLn[512], sRed[8];
  const int t = threadIdx.x, g = blockIdx.x;
  const int w = t >> 6, l = t & 63;
  float c = fmaxf(cnts[g], 1.0f);
  float p = pooledAcc[g * 256 + t] / c;
  outPooled[g * 256 + t] = p;
  sIn[t] = p;
  sIn[256 + t] = qtok[g * 256 + t];
  __syncthreads();
  float a = sIn[t], b = sIn[256 + t];
  float s = a + b, s2 = a * a + b * b;
#pragma unroll
  for (int m = 1; m < 64; m <<= 1) { s += __shfl_xor(s, m); s2 += __shfl_xor(s2, m); }
  if (l == 0) { sRed[w] = s; sRed[4 + w] = s2; }
  __syncthreads();
  s  = sRed[0] + sRed[1] + sRed[2] + sRed[3];
  s2 = sRed[4] + sRed[5] + sRed[6] + sRed[7];
  const float mean = s * (1.0f / 512.0f);
  const float var  = s2 * (1.0f / 512.0f) - mean * mean;
  const float rstd = rsqrtf(var + 1e-5f);
  sLn[t]       = (a - mean) * rstd * ln2g[t] + ln2b[t];
  sLn[256 + t] = (b - mean) * rstd * ln2g[256 + t] + ln2b[256 + t];
  __syncthreads();
  float accv = sb1[t];
#pragma unroll 8
  for (int k = 0; k < 512; ++k) accv += sLn[k] * sW1[k * 256 + t];
  float u = gelu_f(accv);
  float part = u * sW2[t];
#pragma unroll
  for (int m = 1; m < 64; m <<= 1) part += __shfl_xor(part, m);
  if (l == 0) sRed[w] = part;
  __syncthreads();
  if (t == 0) outStop[g] = sRed[0] + sRed[1] + sRed[2] + sRed[3] + sb2[0];
}

// ---------------------------------------------------------------------------
extern "C" void kernel_launch(void* const* d_in, const int* in_sizes, int n_in,
                              void* d_out, int out_size, void* d_ws, size_t ws_size,
                              hipStream_t stream) {
  const float* tok   = (const float*)d_in[0];
  const float* qtok  = (const float*)d_in[1];
  const int* ebatch  = (const int*)d_in[2];
  const void* smask  = d_in[3];
  const int* eheads  = (const int*)d_in[4];
  const int* etails  = (const int*)d_in[5];
  const int* curtail = (const int*)d_in[6];
  const float* ln1g  = (const float*)d_in[7];
  const float* ln1b  = (const float*)d_in[8];
  const float* W1    = (const float*)d_in[9];
  const float* b1    = (const float*)d_in[10];
  const float* W2    = (const float*)d_in[11];
  const float* b2    = (const float*)d_in[12];
  const float* selw  = (const float*)d_in[13];
  const float* selb  = (const float*)d_in[14];
  const float* ln2g  = (const float*)d_in[15];
  const float* ln2b  = (const float*)d_in[16];
  const float* sW1   = (const float*)d_in[17];
  const float* sb1   = (const float*)d_in[18];
  const float* sW2   = (const float*)d_in[19];
  const float* sb2   = (const float*)d_in[20];

  const int E = in_sizes[2];            // 400000
  const int G = in_sizes[1] / 256;      // 64
  const int nTiles = E / EPB;           // 6250
  const int grid = (nTiles + TPB - 1) / TPB;   // 250

  char* ws = (char*)d_ws;
  __bf16* W1p   = (__bf16*)(ws);                 // 131072 B
  __bf16* W2p   = (__bf16*)(ws + 131072);        // 131072 B
  float*  C0    = (float*)(ws + 262144);
  float*  GW6   = (float*)(ws + 263168);
  float*  GW7   = (float*)(ws + 264192);
  float*  pooled= (float*)(ws + 265216);         // 65536 B
  float*  cnts  = (float*)(ws + 330752);         // 256 B
  int*    mflag = (int*)(ws + 331008);           // 4 B
  (void)ws_size; (void)n_in; (void)out_size;

  hipMemsetAsync(ws + 265216, 0, 65536 + 256, stream);  // pooled + counts

  prep_pack<<<64, 256, 0, stream>>>(W1, W2, ln1g, W1p, W2p);
  prep_vec<<<1, 1024, 0, stream>>>(W1, ln1g, ln1b, b1, (const unsigned*)smask,
                                   C0, GW6, GW7, mflag);
  edge_kernel<<<grid, 512, 0, stream>>>(
      tok, ebatch, (const unsigned char*)smask, eheads, etails, curtail,
      W1p, W2p, C0, GW6, GW7, b2, selw, selb, mflag,
      (float*)d_out, pooled, cnts, nTiles);
  stop_kernel<<<G, 256, 0, stream>>>(pooled, cnts, qtok, ln2g, ln2b,
                                     sW1, sb1, sW2, sb2,
                                     (float*)d_out + E, (float*)d_out + E + G);
}

// Round 21
// 281.001 us; speedup vs baseline: 4.3467x; 3.2657x over previous
//
#include <hip/hip_runtime.h>
#include <hip/hip_bf16.h>
#include <cstdint>

// EdgeFrontierPolicy: E=400000, G=64, H=256.
// FINAL (r16 restore, 277us): cooperative 64-edge block, 4 waves, single-pass
// LN with fused flags, A-tile LDS (XOR-swizzled), B-frags streamed from L2
// with reg double-buffer + kt0 preloads hoisted under LN/epilogue, 4 barriers
// per block, launch_bounds(256,3) => 3 waves/SIMD, 80 VGPR + 64 acc, no spill.
// All structural overlap levers (occupancy, prefetch depth, persistence,
// wave-independence, producer/consumer) measured and falsified in r7-r20;
// this phase-sum structure with partial 3-block/CU overlap is the floor.

typedef __bf16 bf16x8 __attribute__((ext_vector_type(8)));
typedef float  f32x4  __attribute__((ext_vector_type(4)));

__device__ __forceinline__ float gelu_f(float x) {
  float x2 = x * x;
  float t1 = __builtin_fmaf(0.1029444f, x2, 2.3022078f);
  float a  = x * t1;
  float e;
  asm("v_exp_f32 %0, %1" : "=v"(e) : "v"(a));
  float r;
  asm("v_rcp_f32 %0, %1" : "=v"(r) : "v"(e + 1.0f));
  return x - x * r;
}

__device__ __forceinline__ bf16x8 as_frag(uint4 u) {
  union { uint4 u; bf16x8 f; } c; c.u = u; return c.f;
}

// ---------------------------------------------------------------------------
// Pack W1 (ln1_g folded) / W2 into MFMA-B fragment order, bf16.
__global__ void prep_pack(const float* __restrict__ W1, const float* __restrict__ W2,
                          const float* __restrict__ ln1g,
                          __bf16* __restrict__ W1p, __bf16* __restrict__ W2p) {
  int gid = blockIdx.x * blockDim.x + threadIdx.x;   // 16384 threads
  int m  = gid >> 13;
  int b  = (gid >> 6) & 127;
  int l  = gid & 63;
  int kt = b >> 4, nt = b & 15;
  int k0 = kt * 32 + ((l >> 4) << 3);
  int n  = nt * 16 + (l & 15);
  const float* W = m ? W2 : W1;
  bf16x8 v;
#pragma unroll
  for (int i = 0; i < 8; ++i) {
    int k = k0 + i;
    float wv = W[k * 256 + n];
    if (!m) wv *= ln1g[k];
    v[i] = (__bf16)wv;
  }
  __bf16* dst = m ? W2p : W1p;
  *(bf16x8*)(dst + (size_t)(b * 64 + l) * 8) = v;
}

// C0/GW6/GW7 + mask dtype detect.
__global__ void prep_vec(const float* __restrict__ W1, const float* __restrict__ ln1g,
                         const float* __restrict__ ln1b, const float* __restrict__ b1,
                         const unsigned* __restrict__ smask_words,
                         float* __restrict__ C0, float* __restrict__ GW6,
                         float* __restrict__ GW7, int* __restrict__ maskIsByte) {
  __shared__ float red[4][256];
  const int n = threadIdx.x & 255, c = threadIdx.x >> 8;
  const int k0 = c * 64, k1 = (c == 3) ? 258 : k0 + 64;
  float s = 0.f;
#pragma unroll 4
  for (int k = k0; k < k1; ++k) s += ln1b[k] * W1[k * 256 + n];
  red[c][n] = s;
  __syncthreads();
  if (c == 0) {
    C0[n]  = b1[n] + red[0][n] + red[1][n] + red[2][n] + red[3][n];
    GW6[n] = ln1g[256] * W1[256 * 256 + n];
    GW7[n] = ln1g[257] * W1[257 * 256 + n];
  }
  if (threadIdx.x == 0) {
    int big = 0;
    for (int i = 0; i < 64; ++i) { if (smask_words[i] > 1u) big = 1; }
    *maskIsByte = big;
  }
}

// ---------------------------------------------------------------------------
#define EPB 64

// 8 K-steps; kt0 B-frags arrive preloaded in bv; depth-1 double-buffer.
__device__ __forceinline__ void gemm8_pre(const char* __restrict__ Wp,
                                          const char* aBase, unsigned swA,
                                          unsigned gA, int bOff,
                                          uint4 (&bv)[4], f32x4 (&acc)[4][4]) {
#pragma unroll
  for (int kt = 0; kt < 8; ++kt) {
    uint4 bn[4];
    if (kt < 7) {
#pragma unroll
      for (int cf = 0; cf < 4; ++cf)
        bn[cf] = *(const uint4*)(Wp + (kt + 1) * 16384 + bOff + (cf << 10));
    }
    bf16x8 av[4];
#pragma unroll
    for (int rf = 0; rf < 4; ++rf)
      av[rf] = *(const bf16x8*)(aBase + rf * 8192 + (((unsigned)(kt * 64) + gA) ^ swA));
#pragma unroll
    for (int rf = 0; rf < 4; ++rf)
#pragma unroll
      for (int cf = 0; cf < 4; ++cf)
        acc[rf][cf] = __builtin_amdgcn_mfma_f32_16x16x32_bf16(av[rf], as_frag(bv[cf]),
                                                              acc[rf][cf], 0, 0, 0);
#pragma unroll
    for (int cf = 0; cf < 4; ++cf) bv[cf] = bn[cf];
  }
}

__global__ __launch_bounds__(256, 3) void edge_kernel(
    const float* __restrict__ tok, const int* __restrict__ ebatch,
    const unsigned char* __restrict__ smaskB,
    const int* __restrict__ eheads, const int* __restrict__ etails,
    const int* __restrict__ curtail,
    const __bf16* __restrict__ W1p, const __bf16* __restrict__ W2p,
    const float* __restrict__ C0v, const float* __restrict__ GW6v,
    const float* __restrict__ GW7v, const float* __restrict__ b2v,
    const float* __restrict__ selwv, const float* __restrict__ selbv,
    const int* __restrict__ maskFlag,
    float* __restrict__ outLogits, float* __restrict__ pooledAcc,
    float* __restrict__ cnts) {
  __shared__ __align__(16) char As_[64 * 512];          // 32KB, XOR-swizzled rows
  __shared__ float sZa0[64], sZa1[64], sFront[64];
  __shared__ float sLog[64][4];
  __shared__ int sG[64];

  const int t = threadIdx.x;
  const int w = t >> 6, l = t & 63;
  const int base = blockIdx.x * EPB;
  const int bOff = (w << 12) + (l << 4);
  const int mb = *maskFlag;

  // hoist: W1-kt0 B-frags (L2) — consumed at GEMM1-kt0, drained under LN
  uint4 wb0[4];
#pragma unroll
  for (int cf = 0; cf < 4; ++cf)
    wb0[cf] = *(const uint4*)((const char*)W1p + bOff + (cf << 10));

  // ---- LN single-pass + fused flags (4 threads/edge, v[16] in regs) ----
  const int e = t >> 2, q = t & 3;
  const int ge = base + e;
  {
    const float* rp = tok + (size_t)ge * 256 + q * 4;
    float4 v[16];
    float s = 0.f, s2 = 0.f;
#pragma unroll
    for (int j = 0; j < 16; ++j) {
      v[j] = *(const float4*)(rp + j * 16);
      s  += v[j].x + v[j].y + v[j].z + v[j].w;
      s2 += v[j].x * v[j].x + v[j].y * v[j].y + v[j].z * v[j].z + v[j].w * v[j].w;
    }
    // flags by this edge's own q==0 lane (same wave) — overlaps the stream above
    float candf = 0.f, frontf = 0.f;
    if (q == 0) {
      int g  = ebatch[ge];
      int mv = mb ? (int)smaskB[ge] : ((const int*)smaskB)[ge];
      int cand = (mv == 0);
      int cur  = curtail[g];
      int fr   = cand && ((eheads[ge] == cur) || (etails[ge] == cur));
      candf = (float)cand; frontf = (float)fr;
      sFront[e] = (float)fr; sG[e] = g;
    }
    const float a0 = __shfl(candf,  l & 60);   // from q==0 lane of this edge
    const float a1 = __shfl(frontf, l & 60);
    s  += __shfl_xor(s, 1);  s  += __shfl_xor(s, 2);
    s2 += __shfl_xor(s2, 1); s2 += __shfl_xor(s2, 2);
    s += a0 + a1; s2 += a0 + a1;               // 0/1 flags: x == x^2
    const float mean = s * (1.0f / 258.0f);
    const float var  = s2 * (1.0f / 258.0f) - mean * mean;
    const float rstd = rsqrtf(var + 1e-5f);
    const float nm   = -mean * rstd;
    const unsigned sw = (unsigned)(e & 7) << 4;
#pragma unroll
    for (int j = 0; j < 16; ++j) {
      union { __bf16 h[4]; uint2 u; } cv;
      cv.h[0] = (__bf16)__builtin_fmaf(v[j].x, rstd, nm);
      cv.h[1] = (__bf16)__builtin_fmaf(v[j].y, rstd, nm);
      cv.h[2] = (__bf16)__builtin_fmaf(v[j].z, rstd, nm);
      cv.h[3] = (__bf16)__builtin_fmaf(v[j].w, rstd, nm);
      unsigned off = (unsigned)(q * 8 + j * 32);
      *(uint2*)(As_ + e * 512 + (off ^ sw)) = cv.u;
    }
    if (q == 0) {
      sZa0[e] = __builtin_fmaf(a0, rstd, nm);
      sZa1[e] = __builtin_fmaf(a1, rstd, nm);
    }
  }
  __syncthreads();   // barrier 1: A tile + za + sG visible

  if (t == 0) {  // counts: run-length over sorted graph ids (overlaps G1)
    int cg = sG[0]; float run = 1.f;
    for (int ee = 1; ee < EPB; ++ee) {
      int g = sG[ee];
      if (g == cg) run += 1.f;
      else { atomicAdd(&cnts[cg], run); cg = g; run = 1.f; }
    }
    atomicAdd(&cnts[cg], run);
  }

  // ---- per-thread geometry + acc init (C0 + rank-2 aux) ----
  const int rA = l & 15;
  const int r0 = (l >> 4) << 2;
  f32x4 acc[4][4];
  {
    float c0r[4], w6r[4], w7r[4];
#pragma unroll
    for (int cf = 0; cf < 4; ++cf) {
      int col = w * 64 + cf * 16 + rA;
      c0r[cf] = C0v[col]; w6r[cf] = GW6v[col]; w7r[cf] = GW7v[col];
    }
    f32x4 za0q[4], za1q[4];
#pragma unroll
    for (int rf = 0; rf < 4; ++rf) {
      za0q[rf] = *(const f32x4*)&sZa0[rf * 16 + r0];
      za1q[rf] = *(const f32x4*)&sZa1[rf * 16 + r0];
    }
#pragma unroll
    for (int rf = 0; rf < 4; ++rf)
#pragma unroll
      for (int cf = 0; cf < 4; ++cf)
#pragma unroll
        for (int i = 0; i < 4; ++i)
          acc[rf][cf][i] = c0r[cf] + za0q[rf][i] * w6r[cf] + za1q[rf][i] * w7r[cf];
  }

  const unsigned swA = (unsigned)(rA & 7) << 4;
  const unsigned gA  = (unsigned)((l >> 4) << 4);
  const char* aBase  = As_ + rA * 512;

  // ---- GEMM1 (B from L2, kt0 preloaded, no barriers) ----
  gemm8_pre((const char*)W1p, aBase, swA, gA, bOff, wb0, acc);
  __syncthreads();   // barrier 2: all GEMM1 A-reads complete

  // hoist: W2-kt0 B-frags — L2 latency hides under epilogue-1's gelu
#pragma unroll
  for (int cf = 0; cf < 4; ++cf)
    wb0[cf] = *(const uint4*)((const char*)W2p + bOff + (cf << 10));

  // ---- epilogue 1: gelu -> bf16 back into A tile ----
#pragma unroll
  for (int rf = 0; rf < 4; ++rf)
#pragma unroll
    for (int i = 0; i < 4; ++i) {
      int row = rf * 16 + r0 + i;
      char* rowp = As_ + row * 512;
      unsigned sw = (unsigned)(row & 7) << 4;
#pragma unroll
      for (int cf = 0; cf < 4; ++cf) {
        int col = w * 64 + cf * 16 + rA;
        *(__bf16*)(rowp + (((unsigned)(col * 2)) ^ sw)) = (__bf16)gelu_f(acc[rf][cf][i]);
      }
    }
  __syncthreads();   // barrier 3: h1 visible

  // ---- GEMM2 ----
#pragma unroll
  for (int cf = 0; cf < 4; ++cf) {
    float bb = b2v[w * 64 + cf * 16 + rA];
#pragma unroll
    for (int rf = 0; rf < 4; ++rf)
#pragma unroll
      for (int i = 0; i < 4; ++i) acc[rf][cf][i] = bb;
  }
  gemm8_pre((const char*)W2p, aBase, swA, gA, bOff, wb0, acc);

  // ---- epilogue 2: gelu -> logits + pooled ----
#pragma unroll
  for (int rf = 0; rf < 4; ++rf)
#pragma unroll
    for (int cf = 0; cf < 4; ++cf)
#pragma unroll
      for (int i = 0; i < 4; ++i) acc[rf][cf][i] = gelu_f(acc[rf][cf][i]);

  {
    float lwr[4];
#pragma unroll
    for (int cf = 0; cf < 4; ++cf) lwr[cf] = selwv[w * 64 + cf * 16 + rA];
#pragma unroll
    for (int rf = 0; rf < 4; ++rf)
#pragma unroll
      for (int i = 0; i < 4; ++i) {
        float p = acc[rf][0][i] * lwr[0] + acc[rf][1][i] * lwr[1]
                + acc[rf][2][i] * lwr[2] + acc[rf][3][i] * lwr[3];
        p += __shfl_xor(p, 1); p += __shfl_xor(p, 2);
        p += __shfl_xor(p, 4); p += __shfl_xor(p, 8);
        if (rA == 0) sLog[rf * 16 + r0 + i][w] = p;
      }
  }
  __syncthreads();   // barrier 4: sLog complete
  if (t < 64)
    outLogits[base + t] = sLog[t][0] + sLog[t][1] + sLog[t][2] + sLog[t][3]
                        + selbv[0] + 0.5f * sFront[t];

  if (sG[0] == sG[EPB - 1]) {
    int g = sG[0];
#pragma unroll
    for (int cf = 0; cf < 4; ++cf) {
      float sv = 0.f;
#pragma unroll
      for (int rf = 0; rf < 4; ++rf)
#pragma unroll
        for (int i = 0; i < 4; ++i) sv += acc[rf][cf][i];
      sv += __shfl_xor(sv, 16);
      sv += __shfl_xor(sv, 32);
      if (l < 16) atomicAdd(&pooledAcc[g * 256 + w * 64 + cf * 16 + l], sv);
    }
  } else {  // graph-boundary block (rare)
#pragma unroll
    for (int rf = 0; rf < 4; ++rf)
#pragma unroll
      for (int i = 0; i < 4; ++i) {
        int row = rf * 16 + r0 + i;
        int g = sG[row];
#pragma unroll
        for (int cf = 0; cf < 4; ++cf)
          atomicAdd(&pooledAcc[g * 256 + w * 64 + cf * 16 + rA], acc[rf][cf][i]);
      }
  }
}

// ---------------------------------------------------------------------------
__global__ __launch_bounds__(256) void stop_kernel(
    const float* __restrict__ pooledAcc, const float* __restrict__ cnts,
    const float* __restrict__ qtok,
    const float* __restrict__ ln2g, const float* __restrict__ ln2b,
    const float* __restrict__ sW1, const float* __restrict__ sb1,
    const float* __restrict__ sW2, const float* __restrict__ sb2,
    float* __restrict__ outStop, float* __restrict__ outPooled) {
  __shared__ float sIn[512], sLn[512], sRed[8];
  const int t = threadIdx.x, g = blockIdx.x;
  const int w = t >> 6, l = t & 63;
  float c = fmaxf(cnts[g], 1.0f);
  float p = pooledAcc[g * 256 + t] / c;
  outPooled[g * 256 + t] = p;
  sIn[t] = p;
  sIn[256 + t] = qtok[g * 256 + t];
  __syncthreads();
  float a = sIn[t], b = sIn[256 + t];
  float s = a + b, s2 = a * a + b * b;
#pragma unroll
  for (int m = 1; m < 64; m <<= 1) { s += __shfl_xor(s, m); s2 += __shfl_xor(s2, m); }
  if (l == 0) { sRed[w] = s; sRed[4 + w] = s2; }
  __syncthreads();
  s  = sRed[0] + sRed[1] + sRed[2] + sRed[3];
  s2 = sRed[4] + sRed[5] + sRed[6] + sRed[7];
  const float mean = s * (1.0f / 512.0f);
  const float var  = s2 * (1.0f / 512.0f) - mean * mean;
  const float rstd = rsqrtf(var + 1e-5f);
  sLn[t]       = (a - mean) * rstd * ln2g[t] + ln2b[t];
  sLn[256 + t] = (b - mean) * rstd * ln2g[256 + t] + ln2b[256 + t];
  __syncthreads();
  float accv = sb1[t];
#pragma unroll 8
  for (int k = 0; k < 512; ++k) accv += sLn[k] * sW1[k * 256 + t];
  float u = gelu_f(accv);
  float part = u * sW2[t];
#pragma unroll
  for (int m = 1; m < 64; m <<= 1) part += __shfl_xor(part, m);
  if (l == 0) sRed[w] = part;
  __syncthreads();
  if (t == 0) outStop[g] = sRed[0] + sRed[1] + sRed[2] + sRed[3] + sb2[0];
}

// ---------------------------------------------------------------------------
extern "C" void kernel_launch(void* const* d_in, const int* in_sizes, int n_in,
                              void* d_out, int out_size, void* d_ws, size_t ws_size,
                              hipStream_t stream) {
  const float* tok   = (const float*)d_in[0];
  const float* qtok  = (const float*)d_in[1];
  const int* ebatch  = (const int*)d_in[2];
  const void* smask  = d_in[3];
  const int* eheads  = (const int*)d_in[4];
  const int* etails  = (const int*)d_in[5];
  const int* curtail = (const int*)d_in[6];
  const float* ln1g  = (const float*)d_in[7];
  const float* ln1b  = (const float*)d_in[8];
  const float* W1    = (const float*)d_in[9];
  const float* b1    = (const float*)d_in[10];
  const float* W2    = (const float*)d_in[11];
  const float* b2    = (const float*)d_in[12];
  const float* selw  = (const float*)d_in[13];
  const float* selb  = (const float*)d_in[14];
  const float* ln2g  = (const float*)d_in[15];
  const float* ln2b  = (const float*)d_in[16];
  const float* sW1   = (const float*)d_in[17];
  const float* sb1   = (const float*)d_in[18];
  const float* sW2   = (const float*)d_in[19];
  const float* sb2   = (const float*)d_in[20];

  const int E = in_sizes[2];            // 400000
  const int G = in_sizes[1] / 256;      // 64

  char* ws = (char*)d_ws;
  __bf16* W1p   = (__bf16*)(ws);                 // 131072 B
  __bf16* W2p   = (__bf16*)(ws + 131072);        // 131072 B
  float*  C0    = (float*)(ws + 262144);
  float*  GW6   = (float*)(ws + 263168);
  float*  GW7   = (float*)(ws + 264192);
  float*  pooled= (float*)(ws + 265216);         // 65536 B
  float*  cnts  = (float*)(ws + 330752);         // 256 B
  int*    mflag = (int*)(ws + 331008);           // 4 B
  (void)ws_size; (void)n_in; (void)out_size;

  hipMemsetAsync(ws + 265216, 0, 65536 + 256, stream);  // pooled + counts

  prep_pack<<<64, 256, 0, stream>>>(W1, W2, ln1g, W1p, W2p);
  prep_vec<<<1, 1024, 0, stream>>>(W1, ln1g, ln1b, b1, (const unsigned*)smask,
                                   C0, GW6, GW7, mflag);
  edge_kernel<<<E / EPB, 256, 0, stream>>>(
      tok, ebatch, (const unsigned char*)smask, eheads, etails, curtail,
      W1p, W2p, C0, GW6, GW7, b2, selw, selb, mflag,
      (float*)d_out, pooled, cnts);
  stop_kernel<<<G, 256, 0, stream>>>(pooled, cnts, qtok, ln2g, ln2b,
                                     sW1, sb1, sW2, sb2,
                                     (float*)d_out + E, (float*)d_out + E + G);
}